// Round 4
// baseline (417.388 us; speedup 1.0000x reference)
//
#include <hip/hip_runtime.h>
#include <stdint.h>

#define NB 32
#define NA 48
#define HIN 64
#define EIN 32
#define HH 64
#define HG 16
#define NCELLS 5
#define GH 1024        // HG*HH
#define EROW 40        // shorts per staged E row (32 + 8 pad; 80 B, 16B-aligned rows)

typedef __attribute__((ext_vector_type(8))) short short8;   // 8 x bf16 (4 VGPRs)
typedef __attribute__((ext_vector_type(4))) float float4v;  // 4 x f32

__device__ __forceinline__ unsigned short f2bf(float f) {
    union { float f; unsigned int u; } v; v.f = f;
    unsigned int u = v.u + 0x7FFF + ((v.u >> 16) & 1);      // round-to-nearest-even
    return (unsigned short)(u >> 16);
}
__device__ __forceinline__ float bf2f(unsigned short s) {
    union { unsigned int u; float f; } v; v.u = ((unsigned int)s) << 16;
    return v.f;
}

// One-shot: W_e [32,1024] fp32 -> split bf16 (hi + lo) in MFMA B-fragment layout.
// slot o = ct*512 + l*8 + jj holds W_e[(l>>4)*8 + jj][ct*16 + (l&15)]
__global__ __launch_bounds__(256) void swizzle_We(const float* __restrict__ W_e,
                                                  unsigned short* __restrict__ hiB,
                                                  unsigned short* __restrict__ loB) {
    const int o  = blockIdx.x * 256 + threadIdx.x;   // 0..32767
    const int ct = o >> 9;
    const int l  = (o >> 3) & 63;
    const int jj = o & 7;
    const int k  = (l >> 4) * 8 + jj;
    const int c  = ct * 16 + (l & 15);
    const float x = W_e[k * GH + c];
    const unsigned short hb = f2bf(x);
    hiB[o] = hb;
    loB[o] = f2bf(x - bf2f(hb));
}

// One block per node (b,j), 256 threads / 4 waves.
__global__ __launch_bounds__(256) void fused_kernel(
    const float* __restrict__ A,  const float* __restrict__ h,
    const float* __restrict__ E,
    const float* __restrict__ W_h, const float* __restrict__ b_h,
    const float* __restrict__ b_e,
    const float* __restrict__ W_ih, const float* __restrict__ b_ih,
    const float* __restrict__ W_hh, const float* __restrict__ b_hh,
    const unsigned short* __restrict__ hiB, const unsigned short* __restrict__ loB,
    float* __restrict__ out)
{
    __shared__ unsigned short EcolH[NA * EROW];  // E[b,:,j,:] bf16 hi
    __shared__ unsigned short EcolL[NA * EROW];  // bf16 lo (residual)
    __shared__ float Esum_s[16 * 68];            // padded stride 68 (conflict-free)
    __shared__ int   ilist[NA];
    __shared__ int   cnt_s;
    __shared__ float hc_s[HH];
    __shared__ float M_s[HG];
    __shared__ float gsum_s[2 * HH];
    __shared__ float gin_s[HH], ghn_s[HH];

    const int node = blockIdx.x;                // b*48 + j
    const int b = node / NA, j = node - b * NA;
    const int tid = threadIdx.x, lane = tid & 63, wave = tid >> 6;
    const int mrow = lane & 15, quad = lane >> 4;

    // ---- stage E[b,:,j,:] -> split bf16 LDS (coalesced float4 per 8 threads/row) ----
    for (int idx = tid; idx < NA * 8; idx += 256) {
        const int r = idx >> 3, q = idx & 7;
        const float4 ev = *(const float4*)(E + ((size_t)(b * NA + r) * NA + j) * EIN + 4 * q);
        unsigned short h0 = f2bf(ev.x), h1 = f2bf(ev.y), h2 = f2bf(ev.z), h3 = f2bf(ev.w);
        unsigned short l0 = f2bf(ev.x - bf2f(h0)), l1 = f2bf(ev.y - bf2f(h1));
        unsigned short l2 = f2bf(ev.z - bf2f(h2)), l3 = f2bf(ev.w - bf2f(h3));
        *(uint2*)(&EcolH[r * EROW + 4 * q]) =
            make_uint2((unsigned int)h0 | ((unsigned int)h1 << 16),
                       (unsigned int)h2 | ((unsigned int)h3 << 16));
        *(uint2*)(&EcolL[r * EROW + 4 * q]) =
            make_uint2((unsigned int)l0 | ((unsigned int)l1 << 16),
                       (unsigned int)l2 | ((unsigned int)l3 << 16));
    }
    // ---- compacted active-row list from column j of A (entries exactly 0/1) ----
    if (tid < 64) {
        if (tid < NA) ilist[tid] = 0;
        const float a = (tid < NA) ? A[((size_t)b * NA + tid) * NA + j] : 0.0f;
        const unsigned long long m = __ballot(a != 0.0f);
        if (a != 0.0f) ilist[__popcll(m & ((1ull << tid) - 1ull))] = tid;
        if (tid == 0) cnt_s = (int)__popcll(m);
    }
    __syncthreads();

    const int cnt = cnt_s;
    const int ntiles = (cnt + 15) >> 4;         // 0..3 row-tiles of compacted edges

    short8 afragH[3], afragL[3];
    float4v mask4[3];
    #pragma unroll
    for (int rt = 0; rt < 3; ++rt) {
        #pragma unroll
        for (int rg = 0; rg < 4; ++rg)
            mask4[rt][rg] = (16 * rt + quad * 4 + rg < cnt) ? 1.0f : 0.0f;
    }
    for (int rt = 0; rt < ntiles; ++rt) {
        const int i = ilist[16 * rt + mrow];
        afragH[rt] = *(const short8*)(&EcolH[i * EROW + quad * 8]);
        afragL[rt] = *(const short8*)(&EcolL[i * EROW + quad * 8]);
    }

    // ---- phase 1: Esum[c] = sum_active_i relu(E_row_i . W_e[:,c] + b_e[c]) ----
    const float4v zero4 = {0.0f, 0.0f, 0.0f, 0.0f};
    for (int t = 0; t < 16; ++t) {
        const int ct = wave * 16 + t;
        const short8 bfH = *(const short8*)(hiB + (size_t)ct * 512 + lane * 8);
        const short8 bfL = *(const short8*)(loB + (size_t)ct * 512 + lane * 8);
        const float be = b_e[ct * 16 + mrow];
        float psum = 0.0f;
        for (int rt = 0; rt < ntiles; ++rt) {
            // split product: A_lo*B_hi + A_hi*B_lo + A_hi*B_hi (fp32 accumulate)
            float4v d = __builtin_amdgcn_mfma_f32_16x16x32_bf16(afragL[rt], bfH, zero4, 0, 0, 0);
            d = __builtin_amdgcn_mfma_f32_16x16x32_bf16(afragH[rt], bfL, d, 0, 0, 0);
            d = __builtin_amdgcn_mfma_f32_16x16x32_bf16(afragH[rt], bfH, d, 0, 0, 0);
            #pragma unroll
            for (int rg = 0; rg < 4; ++rg)
                psum = fmaf(fmaxf(d[rg] + be, 0.0f), mask4[rt][rg], psum);
        }
        psum += __shfl_xor(psum, 16);
        psum += __shfl_xor(psum, 32);
        if (lane < 16) {
            const int c = ct * 16 + lane;
            Esum_s[(c >> 6) * 68 + (c & 63)] = psum;
        }
    }
    __syncthreads();

    // ---- phase 2 setup: gate weights in registers (threads 0..191) ----
    float wih[HG], whh[HH];
    float bihc = 0.0f, bhhc = 0.0f;
    if (tid < 3 * HH) {
        #pragma unroll
        for (int g = 0; g < HG; g += 4) {
            const float4 v = *(const float4*)(W_ih + (size_t)tid * HG + g);
            wih[g] = v.x; wih[g + 1] = v.y; wih[g + 2] = v.z; wih[g + 3] = v.w;
        }
        #pragma unroll
        for (int k = 0; k < HH; k += 4) {
            const float4 v = *(const float4*)(W_hh + (size_t)tid * HH + k);
            whh[k] = v.x; whh[k + 1] = v.y; whh[k + 2] = v.z; whh[k + 3] = v.w;
        }
        bihc = b_ih[tid];
        bhhc = b_hh[tid];
    }
    // hv = relu(h @ W_h + b_h) * maskh  (wave 0; maskh from ROW j of A)
    if (tid < HH) {
        const float a = (lane < NA) ? A[(size_t)node * NA + lane] : 0.0f;
        const unsigned long long mrowm = __ballot(a != 0.0f);
        const float maskh = (mrowm != 0ull) ? 1.0f : 0.0f;
        const float hr = h[(size_t)node * HIN + lane];
        float acc = b_h[lane];
        #pragma unroll
        for (int k = 0; k < HIN; ++k)
            acc = fmaf(__shfl(hr, k), W_h[k * HH + lane], acc);
        hc_s[lane] = fmaxf(acc, 0.0f) * maskh;
    }
    __syncthreads();

    // ---- phase 2: 5 GRUCell iterations ----
    for (int it = 0; it < NCELLS; ++it) {
        {   // M[g] = Esum[g,:] . hc  -- all 256 threads, conflict-free (stride 68)
            const int g = tid >> 4, q = tid & 15;
            const float4v e4 = *(const float4v*)(Esum_s + g * 68 + 4 * q);
            const float4v h4 = *(const float4v*)(hc_s + 4 * q);
            float p = e4[0] * h4[0];
            p = fmaf(e4[1], h4[1], p);
            p = fmaf(e4[2], h4[2], p);
            p = fmaf(e4[3], h4[3], p);
            p += __shfl_xor(p, 1);
            p += __shfl_xor(p, 2);
            p += __shfl_xor(p, 4);
            p += __shfl_xor(p, 8);
            if (q == 0) M_s[g] = p;
        }
        __syncthreads();
        if (tid < 3 * HH) {   // gate pre-activations, weights in registers
            float gi = bihc, gh = bhhc;
            #pragma unroll
            for (int g = 0; g < HG; g += 4) {
                const float4v m4 = *(const float4v*)(M_s + g);
                gi = fmaf(m4[0], wih[g], gi);
                gi = fmaf(m4[1], wih[g + 1], gi);
                gi = fmaf(m4[2], wih[g + 2], gi);
                gi = fmaf(m4[3], wih[g + 3], gi);
            }
            #pragma unroll
            for (int k = 0; k < HH; k += 4) {
                const float4v h4 = *(const float4v*)(hc_s + k);
                gh = fmaf(h4[0], whh[k], gh);
                gh = fmaf(h4[1], whh[k + 1], gh);
                gh = fmaf(h4[2], whh[k + 2], gh);
                gh = fmaf(h4[3], whh[k + 3], gh);
            }
            if (tid < 2 * HH) gsum_s[tid] = gi + gh;            // r,z need only the sum
            else { gin_s[tid - 2 * HH] = gi; ghn_s[tid - 2 * HH] = gh; }
        }
        __syncthreads();
        if (tid < HH) {
            const float r = 1.0f / (1.0f + __expf(-gsum_s[tid]));
            const float z = 1.0f / (1.0f + __expf(-gsum_s[HH + tid]));
            const float nin = gin_s[tid] + r * ghn_s[tid];
            const float n = 1.0f - 2.0f / (__expf(2.0f * nin) + 1.0f);  // tanh
            hc_s[tid] = (1.0f - z) * n + z * hc_s[tid];
        }
        __syncthreads();
    }

    if (tid < HH) out[(size_t)node * HH + tid] = hc_s[tid];
}

extern "C" void kernel_launch(void* const* d_in, const int* in_sizes, int n_in,
                              void* d_out, int out_size, void* d_ws, size_t ws_size,
                              hipStream_t stream) {
    const float* A    = (const float*)d_in[0];
    const float* h    = (const float*)d_in[1];
    const float* E    = (const float*)d_in[2];
    const float* W_h  = (const float*)d_in[3];
    const float* b_h  = (const float*)d_in[4];
    const float* W_e  = (const float*)d_in[5];
    const float* b_e  = (const float*)d_in[6];
    const float* W_ih = (const float*)d_in[7];
    const float* b_ih = (const float*)d_in[8];
    const float* W_hh = (const float*)d_in[9];
    const float* b_hh = (const float*)d_in[10];
    unsigned short* hiB = (unsigned short*)d_ws;            // 64 KB
    unsigned short* loB = hiB + 32768;                      // 64 KB
    float* out = (float*)d_out;

    hipLaunchKernelGGL(swizzle_We, dim3(128), dim3(256), 0, stream, W_e, hiB, loB);
    hipLaunchKernelGGL(fused_kernel, dim3(NB * NA), dim3(256), 0, stream,
                       A, h, E, W_h, b_h, b_e, W_ih, b_ih, W_hh, b_hh, hiB, loB, out);
}

// Round 5
// 134.149 us; speedup vs baseline: 3.1114x; 3.1114x over previous
//
#include <hip/hip_runtime.h>
#include <stdint.h>

#define NB 32
#define NA 48
#define HIN 64
#define EIN 32
#define HH 64
#define HG 16
#define NCELLS 5
#define GH 1024        // HG*HH
#define EROW 40        // shorts per staged E row (32 + 8 pad; 80 B, 16B-aligned rows)

typedef __attribute__((ext_vector_type(8))) short short8;   // 8 x bf16 (4 VGPRs)
typedef __attribute__((ext_vector_type(4))) float float4v;  // 4 x f32

__device__ __forceinline__ unsigned short f2bf(float f) {
    union { float f; unsigned int u; } v; v.f = f;
    unsigned int u = v.u + 0x7FFF + ((v.u >> 16) & 1);      // round-to-nearest-even
    return (unsigned short)(u >> 16);
}
__device__ __forceinline__ float bf2f(unsigned short s) {
    union { unsigned int u; float f; } v; v.u = ((unsigned int)s) << 16;
    return v.f;
}

// One-shot: W_e [32,1024] fp32 -> split bf16 (hi + lo) in MFMA B-fragment layout.
// slot o = ct*512 + l*8 + jj holds W_e[(l>>4)*8 + jj][ct*16 + (l&15)]
__global__ __launch_bounds__(256) void swizzle_We(const float* __restrict__ W_e,
                                                  unsigned short* __restrict__ hiB,
                                                  unsigned short* __restrict__ loB) {
    const int o  = blockIdx.x * 256 + threadIdx.x;   // 0..32767
    const int ct = o >> 9;
    const int l  = (o >> 3) & 63;
    const int jj = o & 7;
    const int k  = (l >> 4) * 8 + jj;
    const int c  = ct * 16 + (l & 15);
    const float x = W_e[k * GH + c];
    const unsigned short hb = f2bf(x);
    hiB[o] = hb;
    loB[o] = f2bf(x - bf2f(hb));
}

// Edge phase specialized on compile-time tile count NT (0..3) so every
// fragment/mask array is constant-indexed -> register-resident (the round-4
// runtime-indexed version spilled to scratch: VALUBusy 57%, MfmaUtil 0.7%).
template <int NT>
__device__ __forceinline__ void edge_phase(
    const unsigned short* __restrict__ hiB, const unsigned short* __restrict__ loB,
    const float* __restrict__ b_e,
    const unsigned short* EcolH, const unsigned short* EcolL,
    const int* ilist, int cnt, int wave, int lane, int mrow, int quad,
    float* Esum_s)
{
    const float4v zero4 = {0.0f, 0.0f, 0.0f, 0.0f};
    short8 aH[NT ? NT : 1], aL[NT ? NT : 1];
    float4v mk[NT ? NT : 1];
    #pragma unroll
    for (int rt = 0; rt < NT; ++rt) {
        const int i = ilist[16 * rt + mrow];
        aH[rt] = *(const short8*)(&EcolH[i * EROW + quad * 8]);
        aL[rt] = *(const short8*)(&EcolL[i * EROW + quad * 8]);
        #pragma unroll
        for (int rg = 0; rg < 4; ++rg)
            mk[rt][rg] = (16 * rt + quad * 4 + rg < cnt) ? 1.0f : 0.0f;
    }
    // biases for this wave's 16 column-tiles, preloaded (constant-indexed)
    float be[16];
    #pragma unroll
    for (int t = 0; t < 16; ++t)
        be[t] = b_e[(wave * 16 + t) * 16 + mrow];

    #pragma unroll 4
    for (int t = 0; t < 16; ++t) {
        const int ct = wave * 16 + t;
        const short8 bfH = *(const short8*)(hiB + (size_t)ct * 512 + lane * 8);
        const short8 bfL = *(const short8*)(loB + (size_t)ct * 512 + lane * 8);
        float psum = 0.0f;
        #pragma unroll
        for (int rt = 0; rt < NT; ++rt) {
            // split-bf16 product: A_lo*B_hi + A_hi*B_lo + A_hi*B_hi (fp32 acc)
            float4v d = __builtin_amdgcn_mfma_f32_16x16x32_bf16(aL[rt], bfH, zero4, 0, 0, 0);
            d = __builtin_amdgcn_mfma_f32_16x16x32_bf16(aH[rt], bfL, d, 0, 0, 0);
            d = __builtin_amdgcn_mfma_f32_16x16x32_bf16(aH[rt], bfH, d, 0, 0, 0);
            #pragma unroll
            for (int rg = 0; rg < 4; ++rg)
                psum = fmaf(fmaxf(d[rg] + be[t], 0.0f), mk[rt][rg], psum);
        }
        psum += __shfl_xor(psum, 16);
        psum += __shfl_xor(psum, 32);
        if (lane < 16) {
            const int c = ct * 16 + lane;
            Esum_s[(c >> 6) * 68 + (c & 63)] = psum;
        }
    }
}

// One block per node (b,j), 256 threads / 4 waves.
__global__ __launch_bounds__(256) void fused_kernel(
    const float* __restrict__ A,  const float* __restrict__ h,
    const float* __restrict__ E,
    const float* __restrict__ W_h, const float* __restrict__ b_h,
    const float* __restrict__ b_e,
    const float* __restrict__ W_ih, const float* __restrict__ b_ih,
    const float* __restrict__ W_hh, const float* __restrict__ b_hh,
    const unsigned short* __restrict__ hiB, const unsigned short* __restrict__ loB,
    float* __restrict__ out)
{
    __shared__ unsigned short EcolH[NA * EROW];  // E[b,:,j,:] bf16 hi
    __shared__ unsigned short EcolL[NA * EROW];  // bf16 lo (residual)
    __shared__ float Esum_s[16 * 68];            // padded stride 68 (conflict-free)
    __shared__ int   ilist[NA];
    __shared__ int   cnt_s;
    __shared__ float hc_s[HH];
    __shared__ float M_s[HG];
    __shared__ float gsum_s[2 * HH];
    __shared__ float gin_s[HH], ghn_s[HH];

    const int node = blockIdx.x;                // b*48 + j
    const int b = node / NA, j = node - b * NA;
    const int tid = threadIdx.x, lane = tid & 63, wave = tid >> 6;
    const int mrow = lane & 15, quad = lane >> 4;

    // ---- stage E[b,:,j,:] -> split bf16 LDS (coalesced float4 per 8 threads/row) ----
    for (int idx = tid; idx < NA * 8; idx += 256) {
        const int r = idx >> 3, q = idx & 7;
        const float4 ev = *(const float4*)(E + ((size_t)(b * NA + r) * NA + j) * EIN + 4 * q);
        unsigned short h0 = f2bf(ev.x), h1 = f2bf(ev.y), h2 = f2bf(ev.z), h3 = f2bf(ev.w);
        unsigned short l0 = f2bf(ev.x - bf2f(h0)), l1 = f2bf(ev.y - bf2f(h1));
        unsigned short l2 = f2bf(ev.z - bf2f(h2)), l3 = f2bf(ev.w - bf2f(h3));
        *(uint2*)(&EcolH[r * EROW + 4 * q]) =
            make_uint2((unsigned int)h0 | ((unsigned int)h1 << 16),
                       (unsigned int)h2 | ((unsigned int)h3 << 16));
        *(uint2*)(&EcolL[r * EROW + 4 * q]) =
            make_uint2((unsigned int)l0 | ((unsigned int)l1 << 16),
                       (unsigned int)l2 | ((unsigned int)l3 << 16));
    }
    // ---- compacted active-row list from column j of A (entries exactly 0/1) ----
    if (tid < 64) {
        if (tid < NA) ilist[tid] = 0;
        const float a = (tid < NA) ? A[((size_t)b * NA + tid) * NA + j] : 0.0f;
        const unsigned long long m = __ballot(a != 0.0f);
        if (a != 0.0f) ilist[__popcll(m & ((1ull << tid) - 1ull))] = tid;
        if (tid == 0) cnt_s = (int)__popcll(m);
    }
    __syncthreads();

    const int cnt = cnt_s;   // block-uniform -> scalar branches below
    if (cnt == 0)
        edge_phase<0>(hiB, loB, b_e, EcolH, EcolL, ilist, cnt, wave, lane, mrow, quad, Esum_s);
    else if (cnt <= 16)
        edge_phase<1>(hiB, loB, b_e, EcolH, EcolL, ilist, cnt, wave, lane, mrow, quad, Esum_s);
    else if (cnt <= 32)
        edge_phase<2>(hiB, loB, b_e, EcolH, EcolL, ilist, cnt, wave, lane, mrow, quad, Esum_s);
    else
        edge_phase<3>(hiB, loB, b_e, EcolH, EcolL, ilist, cnt, wave, lane, mrow, quad, Esum_s);

    // ---- phase 2 setup: gate weights in registers (threads 0..191) ----
    float wih[HG], whh[HH];
    float bihc = 0.0f, bhhc = 0.0f;
    if (tid < 3 * HH) {
        #pragma unroll
        for (int g = 0; g < HG; g += 4) {
            const float4 v = *(const float4*)(W_ih + (size_t)tid * HG + g);
            wih[g] = v.x; wih[g + 1] = v.y; wih[g + 2] = v.z; wih[g + 3] = v.w;
        }
        #pragma unroll
        for (int k = 0; k < HH; k += 4) {
            const float4 v = *(const float4*)(W_hh + (size_t)tid * HH + k);
            whh[k] = v.x; whh[k + 1] = v.y; whh[k + 2] = v.z; whh[k + 3] = v.w;
        }
        bihc = b_ih[tid];
        bhhc = b_hh[tid];
    }
    // hv = relu(h @ W_h + b_h) * maskh  (wave 0; maskh from ROW j of A)
    if (tid < HH) {
        const float a = (lane < NA) ? A[(size_t)node * NA + lane] : 0.0f;
        const unsigned long long mrowm = __ballot(a != 0.0f);
        const float maskh = (mrowm != 0ull) ? 1.0f : 0.0f;
        const float hr = h[(size_t)node * HIN + lane];
        float acc = b_h[lane];
        #pragma unroll
        for (int k = 0; k < HIN; ++k)
            acc = fmaf(__shfl(hr, k), W_h[k * HH + lane], acc);
        hc_s[lane] = fmaxf(acc, 0.0f) * maskh;
    }
    __syncthreads();

    // ---- phase 2: 5 GRUCell iterations ----
    for (int it = 0; it < NCELLS; ++it) {
        {   // M[g] = Esum[g,:] . hc  -- all 256 threads, stride-68 (conflict-free)
            const int g = tid >> 4, q = tid & 15;
            const float4v e4 = *(const float4v*)(Esum_s + g * 68 + 4 * q);
            const float4v h4 = *(const float4v*)(hc_s + 4 * q);
            float p = e4[0] * h4[0];
            p = fmaf(e4[1], h4[1], p);
            p = fmaf(e4[2], h4[2], p);
            p = fmaf(e4[3], h4[3], p);
            p += __shfl_xor(p, 1);
            p += __shfl_xor(p, 2);
            p += __shfl_xor(p, 4);
            p += __shfl_xor(p, 8);
            if (q == 0) M_s[g] = p;
        }
        __syncthreads();
        if (tid < 3 * HH) {   // gate pre-activations; multi-accumulator for ILP
            float gi0 = bihc, gi1 = 0.0f;
            #pragma unroll
            for (int g = 0; g < HG; g += 8) {
                const float4v m4a = *(const float4v*)(M_s + g);
                const float4v m4b = *(const float4v*)(M_s + g + 4);
                gi0 = fmaf(m4a[0], wih[g], gi0);
                gi1 = fmaf(m4a[1], wih[g + 1], gi1);
                gi0 = fmaf(m4a[2], wih[g + 2], gi0);
                gi1 = fmaf(m4a[3], wih[g + 3], gi1);
                gi0 = fmaf(m4b[0], wih[g + 4], gi0);
                gi1 = fmaf(m4b[1], wih[g + 5], gi1);
                gi0 = fmaf(m4b[2], wih[g + 6], gi0);
                gi1 = fmaf(m4b[3], wih[g + 7], gi1);
            }
            float gh0 = bhhc, gh1 = 0.0f, gh2 = 0.0f, gh3 = 0.0f;
            #pragma unroll
            for (int k = 0; k < HH; k += 16) {
                const float4v a4 = *(const float4v*)(hc_s + k);
                const float4v b4 = *(const float4v*)(hc_s + k + 4);
                const float4v c4 = *(const float4v*)(hc_s + k + 8);
                const float4v d4 = *(const float4v*)(hc_s + k + 12);
                gh0 = fmaf(a4[0], whh[k], gh0);      gh1 = fmaf(a4[1], whh[k + 1], gh1);
                gh2 = fmaf(a4[2], whh[k + 2], gh2);  gh3 = fmaf(a4[3], whh[k + 3], gh3);
                gh0 = fmaf(b4[0], whh[k + 4], gh0);  gh1 = fmaf(b4[1], whh[k + 5], gh1);
                gh2 = fmaf(b4[2], whh[k + 6], gh2);  gh3 = fmaf(b4[3], whh[k + 7], gh3);
                gh0 = fmaf(c4[0], whh[k + 8], gh0);  gh1 = fmaf(c4[1], whh[k + 9], gh1);
                gh2 = fmaf(c4[2], whh[k + 10], gh2); gh3 = fmaf(c4[3], whh[k + 11], gh3);
                gh0 = fmaf(d4[0], whh[k + 12], gh0); gh1 = fmaf(d4[1], whh[k + 13], gh1);
                gh2 = fmaf(d4[2], whh[k + 14], gh2); gh3 = fmaf(d4[3], whh[k + 15], gh3);
            }
            const float gi = gi0 + gi1;
            const float gh = (gh0 + gh1) + (gh2 + gh3);
            if (tid < 2 * HH) gsum_s[tid] = gi + gh;            // r,z need only the sum
            else { gin_s[tid - 2 * HH] = gi; ghn_s[tid - 2 * HH] = gh; }
        }
        __syncthreads();
        if (tid < HH) {
            const float r = 1.0f / (1.0f + __expf(-gsum_s[tid]));
            const float z = 1.0f / (1.0f + __expf(-gsum_s[HH + tid]));
            const float nin = gin_s[tid] + r * ghn_s[tid];
            const float n = 1.0f - 2.0f / (__expf(2.0f * nin) + 1.0f);  // tanh
            hc_s[tid] = (1.0f - z) * n + z * hc_s[tid];
        }
        __syncthreads();
    }

    if (tid < HH) out[(size_t)node * HH + tid] = hc_s[tid];
}

extern "C" void kernel_launch(void* const* d_in, const int* in_sizes, int n_in,
                              void* d_out, int out_size, void* d_ws, size_t ws_size,
                              hipStream_t stream) {
    const float* A    = (const float*)d_in[0];
    const float* h    = (const float*)d_in[1];
    const float* E    = (const float*)d_in[2];
    const float* W_h  = (const float*)d_in[3];
    const float* b_h  = (const float*)d_in[4];
    const float* W_e  = (const float*)d_in[5];
    const float* b_e  = (const float*)d_in[6];
    const float* W_ih = (const float*)d_in[7];
    const float* b_ih = (const float*)d_in[8];
    const float* W_hh = (const float*)d_in[9];
    const float* b_hh = (const float*)d_in[10];
    unsigned short* hiB = (unsigned short*)d_ws;            // 64 KB
    unsigned short* loB = hiB + 32768;                      // 64 KB
    float* out = (float*)d_out;

    hipLaunchKernelGGL(swizzle_We, dim3(128), dim3(256), 0, stream, W_e, hiB, loB);
    hipLaunchKernelGGL(fused_kernel, dim3(NB * NA), dim3(256), 0, stream,
                       A, h, E, W_h, b_h, b_e, W_ih, b_ih, W_hh, b_hh, hiB, loB, out);
}